// Round 4
// baseline (309.719 us; speedup 1.0000x reference)
//
#include <hip/hip_runtime.h>
#include <hip/hip_bf16.h>

#define BSZ    2
#define LSEQ   4096
#define DMODEL 2048
#define DTR    128
#define DST    16
#define ODIM   160            // DTR + 2*DST
#define MROWS  (BSZ*LSEQ)     // 8192
#define CH     64             // chunks along L
#define TT     (LSEQ/CH)      // 64 steps per chunk
#define LOG2E  1.44269504088896340736f
#define LN2    0.69314718055994530942f

typedef short  short8  __attribute__((ext_vector_type(8)));
typedef float  floatx4 __attribute__((ext_vector_type(4)));

__device__ __forceinline__ unsigned short f2bf(float f) {
    unsigned u = __float_as_uint(f);
    u += 0x7fffu + ((u >> 16) & 1u);      // round-to-nearest-even
    return (unsigned short)(u >> 16);
}
__device__ __forceinline__ float quantv(float x, float s, float inv_s) {
    float q = rintf(x * inv_s);
    q = fminf(fmaxf(q, -128.0f), 127.0f);
    return q * s;
}
__device__ __forceinline__ float softplus_fast(float v) {
    float t = __builtin_amdgcn_exp2f(-fabsf(v) * LOG2E);
    return fmaxf(v, 0.0f) + LN2 * __log2f(1.0f + t);
}
__device__ __forceinline__ float scale_from_bits(unsigned bits) {
    return fmaxf(__uint_as_float(bits) * (1.0f/127.0f), 1e-8f);
}
// packed MFMA-fragment offset for row-major [R x K], 16x16x32 frags
__device__ __forceinline__ int pidx(int r, int k, int K) {
    return (r >> 4)*(16*K) + ((k >> 5) << 9) + (((r & 15) + (((k & 31) >> 3) << 4)) << 3) + (k & 7);
}

// ---------------------------------------------------------------- prep ------
#define PB_WX  160
#define PB_WDT 128
#define PB_A   128
#define PB_D   1
#define PREP_BLOCKS (PB_WX + PB_WDT + PB_A + PB_D)

__global__ __launch_bounds__(256) void k_prep(
    const float* __restrict__ Wx, const float* __restrict__ Wdt,
    const float* __restrict__ A_log, const float* __restrict__ Dskip,
    unsigned short* __restrict__ Wxq, unsigned short* __restrict__ Wdtq,
    float* __restrict__ a2, float* __restrict__ Dq)
{
    int bid = blockIdx.x, tid = threadIdx.x;
    __shared__ float red[256];
    if (bid < PB_WX) {                       // Wx row: per-channel quant -> packed bf16
        int o = bid, base = o * DMODEL;
        float m = 0.0f;
        for (int i = tid; i < DMODEL; i += 256) m = fmaxf(m, fabsf(Wx[base+i]));
        red[tid] = m; __syncthreads();
        for (int s2 = 128; s2 > 0; s2 >>= 1) { if (tid < s2) red[tid] = fmaxf(red[tid], red[tid+s2]); __syncthreads(); }
        float s = fmaxf(red[0]*(1.0f/127.0f), 1e-8f), inv = 1.0f/s;
        for (int i = tid; i < DMODEL; i += 256)
            Wxq[pidx(o, i, DMODEL)] = f2bf(quantv(Wx[base+i], s, inv));
    } else if (bid < PB_WX + PB_WDT) {       // Wdt n-tile: 16 rows, 8 elems/thread
        int n = (bid - PB_WX)*16 + (tid >> 4);
        int k0 = (tid & 15)*8;
        const float* src = Wdt + (size_t)n*DTR + k0;
        float4 v0 = *reinterpret_cast<const float4*>(src);
        float4 v1 = *reinterpret_cast<const float4*>(src + 4);
        float m = fmaxf(fmaxf(fmaxf(fabsf(v0.x), fabsf(v0.y)), fmaxf(fabsf(v0.z), fabsf(v0.w))),
                        fmaxf(fmaxf(fabsf(v1.x), fabsf(v1.y)), fmaxf(fabsf(v1.z), fabsf(v1.w))));
        for (int off = 1; off < 16; off <<= 1) m = fmaxf(m, __shfl_xor(m, off, 16));
        float s = fmaxf(m*(1.0f/127.0f), 1e-8f), inv = 1.0f/s;
        short8 o8;
        o8[0]=(short)f2bf(quantv(v0.x,s,inv)); o8[1]=(short)f2bf(quantv(v0.y,s,inv));
        o8[2]=(short)f2bf(quantv(v0.z,s,inv)); o8[3]=(short)f2bf(quantv(v0.w,s,inv));
        o8[4]=(short)f2bf(quantv(v1.x,s,inv)); o8[5]=(short)f2bf(quantv(v1.y,s,inv));
        o8[6]=(short)f2bf(quantv(v1.z,s,inv)); o8[7]=(short)f2bf(quantv(v1.w,s,inv));
        *reinterpret_cast<short8*>(Wdtq + pidx(n, k0, DTR)) = o8;
    } else if (bid < PB_WX + PB_WDT + PB_A) { // A_log -> a2 = -exp(q)*log2e
        int d = (bid - PB_WX - PB_WDT)*16 + (tid >> 4);
        int n = tid & 15;
        float v = A_log[d*DST + n];
        float m = fabsf(v);
        for (int off = 1; off < 16; off <<= 1) m = fmaxf(m, __shfl_xor(m, off, 16));
        float s = fmaxf(m*(1.0f/127.0f), 1e-8f);
        float q = quantv(v, s, 1.0f/s);
        a2[d*DST + n] = -expf(q) * LOG2E;
    } else {                                  // Dskip per-tensor quant
        float m = 0.0f;
        for (int i = tid; i < DMODEL; i += 256) m = fmaxf(m, fabsf(Dskip[i]));
        red[tid] = m; __syncthreads();
        for (int s2 = 128; s2 > 0; s2 >>= 1) { if (tid < s2) red[tid] = fmaxf(red[tid], red[tid+s2]); __syncthreads(); }
        float s = fmaxf(red[0]*(1.0f/127.0f), 1e-8f), inv = 1.0f/s;
        for (int i = tid; i < DMODEL; i += 256) Dq[i] = quantv(Dskip[i], s, inv);
    }
}

// ------ GEMM1 fused: 4 waves = 4 K-chunks of one 16-row tile, LDS-reduced ---
__global__ __launch_bounds__(256) void k_mm1(
    const float* __restrict__ x, const unsigned short* __restrict__ Wxq,
    const float* __restrict__ prompt,
    unsigned short* __restrict__ xdblbf, float* __restrict__ xbc,
    unsigned* __restrict__ scales)
{
    int tid = threadIdx.x, w = tid >> 6, lane = tid & 63;
    int mrow = lane & 15, quad = lane >> 4;
    int mt = blockIdx.x, m0 = mt*16, k0 = w*512;
    floatx4 acc[10] = {};
    float xmax = 0.0f;
    const float* arow = x + (size_t)(m0 + mrow)*DMODEL + k0 + quad*8;
    for (int kk = 0; kk < 512; kk += 32) {
        const float4* ap = reinterpret_cast<const float4*>(arow + kk);
        float4 a0 = ap[0], a1 = ap[1];
        xmax = fmaxf(xmax, fmaxf(fmaxf(fabsf(a0.x), fabsf(a0.y)), fmaxf(fabsf(a0.z), fabsf(a0.w))));
        xmax = fmaxf(xmax, fmaxf(fmaxf(fabsf(a1.x), fabsf(a1.y)), fmaxf(fabsf(a1.z), fabsf(a1.w))));
        short8 af;
        af[0]=(short)f2bf(a0.x); af[1]=(short)f2bf(a0.y); af[2]=(short)f2bf(a0.z); af[3]=(short)f2bf(a0.w);
        af[4]=(short)f2bf(a1.x); af[5]=(short)f2bf(a1.y); af[6]=(short)f2bf(a1.z); af[7]=(short)f2bf(a1.w);
        int kcidx = (k0 + kk) >> 5;
        #pragma unroll
        for (int j = 0; j < 10; ++j) {
            short8 bf = *reinterpret_cast<const short8*>(Wxq + j*16*DMODEL + kcidx*512 + lane*8);
            acc[j] = __builtin_amdgcn_mfma_f32_16x16x32_bf16(af, bf, acc[j], 0, 0, 0);
        }
    }
    for (int off = 32; off; off >>= 1) xmax = fmaxf(xmax, __shfl_xor(xmax, off, 64));
    __shared__ float red[4*2560];
    __shared__ float redB[256], redC[256];
    __shared__ float wred[4];
    if (lane == 0) wred[w] = xmax;
    #pragma unroll
    for (int j = 0; j < 10; ++j) {
        float4 v = make_float4(acc[j][0], acc[j][1], acc[j][2], acc[j][3]);
        *reinterpret_cast<float4*>(&red[w*2560 + (j*16 + mrow)*16 + quad*4]) = v;
    }
    __syncthreads();
    float bmax = 0.0f, cmax = 0.0f;
    #pragma unroll
    for (int j = 0; j < 10; ++j) {
        int e = j*256 + tid;
        float v = red[e] + red[2560+e] + red[5120+e] + red[7680+e];
        int col = e >> 4, rowin = e & 15, row = m0 + rowin;
        if (col < DTR) {
            xdblbf[mt*16*DTR + ((col>>5)<<9) + ((rowin + (((col&31)>>3)<<4))<<3) + (col&7)] = f2bf(v);
        } else if (col < DTR + DST) {
            bmax = fmaxf(bmax, fabsf(v));
            xbc[(size_t)row*32 + (col - DTR)] = v;
        } else {
            v += prompt[(size_t)row*DST + (col - DTR - DST)];
            cmax = fmaxf(cmax, fabsf(v));
            xbc[(size_t)row*32 + 16 + (col - DTR - DST)] = v;
        }
    }
    redB[tid] = bmax; redC[tid] = cmax; __syncthreads();
    for (int s2 = 128; s2 > 0; s2 >>= 1) {
        if (tid < s2) { redB[tid] = fmaxf(redB[tid], redB[tid+s2]); redC[tid] = fmaxf(redC[tid], redC[tid+s2]); }
        __syncthreads();
    }
    if (tid == 0) {
        atomicMax(&scales[0], __float_as_uint(fmaxf(fmaxf(wred[0], wred[1]), fmaxf(wred[2], wred[3]))));
        atomicMax(&scales[1], __float_as_uint(redB[0]));
        atomicMax(&scales[2], __float_as_uint(redC[0]));
    }
}

// ---- GEMM2 max-only pass (result discarded) + fused x -> int8 quantization -
__global__ __launch_bounds__(256) void k_dmaxu(
    const unsigned short* __restrict__ Ap, const unsigned short* __restrict__ Bp,
    const float* __restrict__ bdt, const float* __restrict__ x,
    signed char* __restrict__ u8, unsigned* __restrict__ scales)
{
    int tid = threadIdx.x, w = tid >> 6, lane = tid & 63;
    int mrow = lane & 15;
    int mt = blockIdx.x >> 4, nt = blockIdx.x & 15;
    int mtile = mt*4 + w, n0 = nt*128;
    short8 afr[4];
    const unsigned short* ab = Ap + (size_t)mtile*16*DTR + lane*8;
    #pragma unroll
    for (int kc = 0; kc < 4; ++kc) afr[kc] = *reinterpret_cast<const short8*>(ab + (kc<<9));
    float dmax = 0.0f;
    #pragma unroll
    for (int j = 0; j < 8; ++j) {
        const unsigned short* bb = Bp + (size_t)(n0/16 + j)*16*DTR + lane*8;
        floatx4 acc = {};
        #pragma unroll
        for (int kc = 0; kc < 4; ++kc) {
            short8 bf = *reinterpret_cast<const short8*>(bb + (kc<<9));
            acc = __builtin_amdgcn_mfma_f32_16x16x32_bf16(afr[kc], bf, acc, 0, 0, 0);
        }
        float bv = bdt[n0 + j*16 + mrow];
        #pragma unroll
        for (int r = 0; r < 4; ++r) dmax = fmaxf(dmax, fabsf(acc[r] + bv));
    }
    // fused u8 quantization: this block's 8192-float slice of x
    float s_u = scale_from_bits(scales[0]);
    float inv_su = 1.0f / s_u;
    const float4* xs = reinterpret_cast<const float4*>(x) + (size_t)blockIdx.x*2048;
    unsigned* uo = reinterpret_cast<unsigned*>(u8) + (size_t)blockIdx.x*2048;
    #pragma unroll
    for (int i = 0; i < 8; ++i) {
        float4 v = xs[i*256 + tid];
        int q0 = (int)fminf(fmaxf(rintf(v.x*inv_su), -128.0f), 127.0f);
        int q1 = (int)fminf(fmaxf(rintf(v.y*inv_su), -128.0f), 127.0f);
        int q2 = (int)fminf(fmaxf(rintf(v.z*inv_su), -128.0f), 127.0f);
        int q3 = (int)fminf(fmaxf(rintf(v.w*inv_su), -128.0f), 127.0f);
        uo[i*256 + tid] = (q0 & 255) | ((q1 & 255) << 8) | ((q2 & 255) << 16) | ((unsigned)(q3 & 255) << 24);
    }
    for (int off = 32; off; off >>= 1) dmax = fmaxf(dmax, __shfl_xor(dmax, off, 64));
    __shared__ float wd[4];
    if (lane == 0) wd[w] = dmax;
    __syncthreads();
    if (tid == 0)
        atomicMax(&scales[3], __float_as_uint(fmaxf(fmaxf(wd[0], wd[1]), fmaxf(wd[2], wd[3]))));
}

// ---------------- scan phase 1: recompute dts tile in-block, chunk aggregates
__global__ __launch_bounds__(256) void k_scan1(
    const unsigned short* __restrict__ Ap, const unsigned short* __restrict__ Bp,
    const float* __restrict__ bdt, const signed char* __restrict__ u8,
    const float* __restrict__ xbc, const float* __restrict__ a2,
    const unsigned* __restrict__ scales,
    float* __restrict__ Aprod, float* __restrict__ hfin)
{
    int bid = blockIdx.x, tid = threadIdx.x;
    int w = tid >> 6, lane = tid & 63;
    int mrow = lane & 15, quad = lane >> 4;
    int b = bid >> 9, rem = bid & 511, dblk = rem >> 6, ch = rem & 63;
    int d0 = dblk*256, t0 = ch*TT;
    int d = d0 + tid;
    float s_u  = scale_from_bits(scales[0]);
    float s_B  = scale_from_bits(scales[1]), inv_sB  = 1.0f/s_B;
    float s_dt = scale_from_bits(scales[3]), inv_sdt = 1.0f/s_dt;
    float a2r[16];
    {
        const float4* ap = reinterpret_cast<const float4*>(a2 + (size_t)d*DST);
        float4 v0 = ap[0], v1 = ap[1], v2 = ap[2], v3 = ap[3];
        a2r[0]=v0.x; a2r[1]=v0.y; a2r[2]=v0.z; a2r[3]=v0.w;
        a2r[4]=v1.x; a2r[5]=v1.y; a2r[6]=v1.z; a2r[7]=v1.w;
        a2r[8]=v2.x; a2r[9]=v2.y; a2r[10]=v2.z; a2r[11]=v2.w;
        a2r[12]=v3.x; a2r[13]=v3.y; a2r[14]=v3.z; a2r[15]=v3.w;
    }
    float h[16];
    #pragma unroll
    for (int n = 0; n < 16; ++n) h[n] = 0.0f;
    float sdt = 0.0f;
    __shared__ float lds_dts[32*256];          // 32 KB
    __shared__ unsigned lds_u[32*64];          // 8 KB
    __shared__ __align__(16) float Bq_p[32*16];
    for (int st = 0; st < 2; ++st) {
        int tb = t0 + st*32;
        // ---- MFMA: dts tile [32 t x 256 d] -> LDS (order matches k_dmaxu) --
        int gm0 = (b*LSEQ + tb) >> 4;
        short8 afr[2][4];
        #pragma unroll
        for (int rt = 0; rt < 2; ++rt)
            #pragma unroll
            for (int kc = 0; kc < 4; ++kc)
                afr[rt][kc] = *reinterpret_cast<const short8*>(Ap + (size_t)(gm0+rt)*16*DTR + (kc<<9) + lane*8);
        #pragma unroll
        for (int j = 0; j < 4; ++j) {
            int ntile = dblk*16 + w*4 + j;
            int dloc = w*64 + j*16 + mrow;
            float bdtv = bdt[d0 + dloc];
            short8 bfr[4];
            #pragma unroll
            for (int kc = 0; kc < 4; ++kc)
                bfr[kc] = *reinterpret_cast<const short8*>(Bp + (size_t)ntile*16*DTR + (kc<<9) + lane*8);
            #pragma unroll
            for (int rt = 0; rt < 2; ++rt) {
                floatx4 acc = {};
                #pragma unroll
                for (int kc = 0; kc < 4; ++kc)
                    acc = __builtin_amdgcn_mfma_f32_16x16x32_bf16(afr[rt][kc], bfr[kc], acc, 0, 0, 0);
                #pragma unroll
                for (int r = 0; r < 4; ++r)
                    lds_dts[(rt*16 + quad*4 + r)*256 + dloc] = acc[r] + bdtv;
            }
        }
        // ---- stage u8 (as dwords) + quantized B ----
        {
            const unsigned* ub = reinterpret_cast<const unsigned*>(u8 + (size_t)(b*LSEQ + tb)*DMODEL + d0);
            #pragma unroll
            for (int i = 0; i < 8; ++i) {
                int q = i*256 + tid;
                lds_u[q] = ub[(q >> 6)*(DMODEL/4) + (q & 63)];
            }
            int e = tid;
            Bq_p[e] = quantv(xbc[(size_t)(b*LSEQ + tb + (e>>4))*32 + (e&15)], s_B, inv_sB);
            e = tid + 256;
            Bq_p[e] = quantv(xbc[(size_t)(b*LSEQ + tb + (e>>4))*32 + (e&15)], s_B, inv_sB);
        }
        __syncthreads();
        const signed char* lub = reinterpret_cast<const signed char*>(lds_u);
        for (int t = 0; t < 32; ++t) {
            float dtq = quantv(lds_dts[t*256 + tid], s_dt, inv_sdt);
            float dtv = softplus_fast(dtq);
            float uq  = s_u * (float)lub[t*256 + tid];
            float dtu = dtv * uq;
            sdt += dtv;
            const float4* bq4 = reinterpret_cast<const float4*>(&Bq_p[t*16]);
            float4 b0 = bq4[0], b1 = bq4[1], b2 = bq4[2], b3 = bq4[3];
            float bq[16] = { b0.x,b0.y,b0.z,b0.w, b1.x,b1.y,b1.z,b1.w,
                             b2.x,b2.y,b2.z,b2.w, b3.x,b3.y,b3.z,b3.w };
            #pragma unroll
            for (int n = 0; n < 16; ++n) {
                float dA = __builtin_amdgcn_exp2f(a2r[n]*dtv);
                h[n] = fmaf(dA, h[n], dtu*bq[n]);
            }
        }
        __syncthreads();
    }
    size_t ob = ((size_t)((b*CH + ch)*DMODEL + d))*DST;
    #pragma unroll
    for (int i = 0; i < 4; ++i) {
        float4 av = make_float4(__builtin_amdgcn_exp2f(a2r[4*i+0]*sdt),
                                __builtin_amdgcn_exp2f(a2r[4*i+1]*sdt),
                                __builtin_amdgcn_exp2f(a2r[4*i+2]*sdt),
                                __builtin_amdgcn_exp2f(a2r[4*i+3]*sdt));
        float4 hv = make_float4(h[4*i+0], h[4*i+1], h[4*i+2], h[4*i+3]);
        *reinterpret_cast<float4*>(Aprod + ob + 4*i) = av;
        *reinterpret_cast<float4*>(hfin  + ob + 4*i) = hv;
    }
}

// ------------------------- scan phase 2: across-chunk recurrence (in-place) -
__global__ __launch_bounds__(256) void k_mid(
    float* __restrict__ Aprod, const float* __restrict__ hfin)
{
    int f = blockIdx.x*256 + threadIdx.x;      // 65536 = B*DMODEL*DST
    int b = f >> 15, dn = f & 32767;
    size_t base = (size_t)b*CH*32768 + dn;
    float h = 0.0f;
    #pragma unroll 4
    for (int ch = 0; ch < CH; ++ch) {
        size_t o = base + (size_t)ch*32768;
        float a = Aprod[o], hf = hfin[o];
        Aprod[o] = h;                          // exclusive prefix -> h_init
        h = fmaf(a, h, hf);
    }
}

// ------------- scan phase 3: recompute dts tile, replay, y + u_q*D_q -> out -
__global__ __launch_bounds__(256) void k_scan3(
    const unsigned short* __restrict__ Ap, const unsigned short* __restrict__ Bp,
    const float* __restrict__ bdt, const signed char* __restrict__ u8,
    const float* __restrict__ xbc, const float* __restrict__ a2,
    const float* __restrict__ Dq, const unsigned* __restrict__ scales,
    const float* __restrict__ hinit, float* __restrict__ out)
{
    int bid = blockIdx.x, tid = threadIdx.x;
    int w = tid >> 6, lane = tid & 63;
    int mrow = lane & 15, quad = lane >> 4;
    int b = bid >> 9, rem = bid & 511, dblk = rem >> 6, ch = rem & 63;
    int d0 = dblk*256, t0 = ch*TT;
    int d = d0 + tid;
    float s_u  = scale_from_bits(scales[0]);
    float s_B  = scale_from_bits(scales[1]), inv_sB  = 1.0f/s_B;
    float s_C  = scale_from_bits(scales[2]), inv_sC  = 1.0f/s_C;
    float s_dt = scale_from_bits(scales[3]), inv_sdt = 1.0f/s_dt;
    float dqd = Dq[d];
    float a2r[16];
    {
        const float4* ap = reinterpret_cast<const float4*>(a2 + (size_t)d*DST);
        float4 v0 = ap[0], v1 = ap[1], v2 = ap[2], v3 = ap[3];
        a2r[0]=v0.x; a2r[1]=v0.y; a2r[2]=v0.z; a2r[3]=v0.w;
        a2r[4]=v1.x; a2r[5]=v1.y; a2r[6]=v1.z; a2r[7]=v1.w;
        a2r[8]=v2.x; a2r[9]=v2.y; a2r[10]=v2.z; a2r[11]=v2.w;
        a2r[12]=v3.x; a2r[13]=v3.y; a2r[14]=v3.z; a2r[15]=v3.w;
    }
    size_t ob = ((size_t)((b*CH + ch)*DMODEL + d))*DST;
    float h[16];
    #pragma unroll
    for (int i = 0; i < 4; ++i) {
        float4 hv = *reinterpret_cast<const float4*>(hinit + ob + 4*i);
        h[4*i+0]=hv.x; h[4*i+1]=hv.y; h[4*i+2]=hv.z; h[4*i+3]=hv.w;
    }
    __shared__ float lds_dts[32*256];
    __shared__ unsigned lds_u[32*64];
    __shared__ __align__(16) float Bq_p[32*16];
    __shared__ __align__(16) float Cq_p[32*16];
    for (int st = 0; st < 2; ++st) {
        int tb = t0 + st*32;
        int gm0 = (b*LSEQ + tb) >> 4;
        short8 afr[2][4];
        #pragma unroll
        for (int rt = 0; rt < 2; ++rt)
            #pragma unroll
            for (int kc = 0; kc < 4; ++kc)
                afr[rt][kc] = *reinterpret_cast<const short8*>(Ap + (size_t)(gm0+rt)*16*DTR + (kc<<9) + lane*8);
        #pragma unroll
        for (int j = 0; j < 4; ++j) {
            int ntile = dblk*16 + w*4 + j;
            int dloc = w*64 + j*16 + mrow;
            float bdtv = bdt[d0 + dloc];
            short8 bfr[4];
            #pragma unroll
            for (int kc = 0; kc < 4; ++kc)
                bfr[kc] = *reinterpret_cast<const short8*>(Bp + (size_t)ntile*16*DTR + (kc<<9) + lane*8);
            #pragma unroll
            for (int rt = 0; rt < 2; ++rt) {
                floatx4 acc = {};
                #pragma unroll
                for (int kc = 0; kc < 4; ++kc)
                    acc = __builtin_amdgcn_mfma_f32_16x16x32_bf16(afr[rt][kc], bfr[kc], acc, 0, 0, 0);
                #pragma unroll
                for (int r = 0; r < 4; ++r)
                    lds_dts[(rt*16 + quad*4 + r)*256 + dloc] = acc[r] + bdtv;
            }
        }
        {
            const unsigned* ub = reinterpret_cast<const unsigned*>(u8 + (size_t)(b*LSEQ + tb)*DMODEL + d0);
            #pragma unroll
            for (int i = 0; i < 8; ++i) {
                int q = i*256 + tid;
                lds_u[q] = ub[(q >> 6)*(DMODEL/4) + (q & 63)];
            }
            int e = tid;
            size_t px = (size_t)(b*LSEQ + tb + (e>>4))*32;
            Bq_p[e] = quantv(xbc[px + (e&15)],      s_B, inv_sB);
            Cq_p[e] = quantv(xbc[px + 16 + (e&15)], s_C, inv_sC);
            e = tid + 256;
            px = (size_t)(b*LSEQ + tb + (e>>4))*32;
            Bq_p[e] = quantv(xbc[px + (e&15)],      s_B, inv_sB);
            Cq_p[e] = quantv(xbc[px + 16 + (e&15)], s_C, inv_sC);
        }
        __syncthreads();
        const signed char* lub = reinterpret_cast<const signed char*>(lds_u);
        for (int t = 0; t < 32; ++t) {
            float dtq = quantv(lds_dts[t*256 + tid], s_dt, inv_sdt);
            float dtv = softplus_fast(dtq);
            float uq  = s_u * (float)lub[t*256 + tid];
            float dtu = dtv * uq;
            const float4* bq4 = reinterpret_cast<const float4*>(&Bq_p[t*16]);
            const float4* cq4 = reinterpret_cast<const float4*>(&Cq_p[t*16]);
            float4 b0 = bq4[0], b1 = bq4[1], b2 = bq4[2], b3 = bq4[3];
            float4 c0 = cq4[0], c1 = cq4[1], c2 = cq4[2], c3 = cq4[3];
            float bq[16] = { b0.x,b0.y,b0.z,b0.w, b1.x,b1.y,b1.z,b1.w,
                             b2.x,b2.y,b2.z,b2.w, b3.x,b3.y,b3.z,b3.w };
            float cq[16] = { c0.x,c0.y,c0.z,c0.w, c1.x,c1.y,c1.z,c1.w,
                             c2.x,c2.y,c2.z,c2.w, c3.x,c3.y,c3.z,c3.w };
            float y = 0.0f;
            #pragma unroll
            for (int n = 0; n < 16; ++n) {
                float dA = __builtin_amdgcn_exp2f(a2r[n]*dtv);
                h[n] = fmaf(dA, h[n], dtu*bq[n]);
                y = fmaf(h[n], cq[n], y);
            }
            __builtin_nontemporal_store(y + uq * dqd, out + (size_t)(b*LSEQ + tb + t)*DMODEL + d);
        }
        __syncthreads();
    }
}

// ---------------------------------------------------------------------------
extern "C" void kernel_launch(void* const* d_in, const int* in_sizes, int n_in,
                              void* d_out, int out_size, void* d_ws, size_t ws_size,
                              hipStream_t stream)
{
    const float* x      = (const float*)d_in[0];
    const float* prompt = (const float*)d_in[1];
    const float* Wx     = (const float*)d_in[2];
    const float* Wdt    = (const float*)d_in[3];
    const float* bdt    = (const float*)d_in[4];
    const float* A_log  = (const float*)d_in[5];
    const float* Dskip  = (const float*)d_in[6];
    float* out = (float*)d_out;
    char* ws = (char*)d_ws;
    size_t off = 0;
    unsigned* scales       = (unsigned*)(ws + off);        off += 256;
    unsigned short* Wxq    = (unsigned short*)(ws + off);  off += (size_t)ODIM*DMODEL*2;
    unsigned short* Wdtq   = (unsigned short*)(ws + off);  off += (size_t)DMODEL*DTR*2;
    float* a2              = (float*)(ws + off);           off += (size_t)DMODEL*DST*4;
    float* Dq              = (float*)(ws + off);           off += (size_t)DMODEL*4;
    float* xbc             = (float*)(ws + off);           off += (size_t)MROWS*32*4;
    unsigned short* xdblbf = (unsigned short*)(ws + off);  off += (size_t)MROWS*DTR*2;
    signed char* u8        = (signed char*)(ws + off);     off += (size_t)MROWS*DMODEL;
    float* Aprod           = (float*)(ws + off);           off += (size_t)BSZ*CH*DMODEL*DST*4;
    float* hfin            = (float*)(ws + off);           off += (size_t)BSZ*CH*DMODEL*DST*4;

    hipMemsetAsync(scales, 0, 256, stream);
    hipLaunchKernelGGL(k_prep, dim3(PREP_BLOCKS), dim3(256), 0, stream,
                       Wx, Wdt, A_log, Dskip, Wxq, Wdtq, a2, Dq);
    hipLaunchKernelGGL(k_mm1, dim3(MROWS/16), dim3(256), 0, stream,
                       x, Wxq, prompt, xdblbf, xbc, scales);
    hipLaunchKernelGGL(k_dmaxu, dim3((MROWS/64)*(DMODEL/128)), dim3(256), 0, stream,
                       xdblbf, Wdtq, bdt, x, u8, scales);
    hipLaunchKernelGGL(k_scan1, dim3(BSZ*8*CH), dim3(256), 0, stream,
                       xdblbf, Wdtq, bdt, u8, xbc, a2, scales, Aprod, hfin);
    hipLaunchKernelGGL(k_mid, dim3(BSZ*DMODEL*DST/256), dim3(256), 0, stream,
                       Aprod, hfin);
    hipLaunchKernelGGL(k_scan3, dim3(BSZ*8*CH), dim3(256), 0, stream,
                       xdblbf, Wdtq, bdt, u8, xbc, a2, Dq, scales, Aprod, out);
}